// Round 6
// baseline (502.520 us; speedup 1.0000x reference)
//
#include <hip/hip_runtime.h>

typedef __attribute__((ext_vector_type(8))) short short8;
typedef __attribute__((ext_vector_type(4))) float floatx4;

__device__ __forceinline__ unsigned short f2b(float f) {
  unsigned int u = __float_as_uint(f);
  unsigned int r = (u + 0x7FFFu + ((u >> 16) & 1u)) >> 16;  // RNE
  return (unsigned short)r;
}
// load 8 fp32, convert to 8 bf16 packed in a uint4
__device__ __forceinline__ uint4 ld8f(const float* p) {
  float4 a = *(const float4*)p;
  float4 b = *(const float4*)(p + 4);
  uint4 r;
  r.x = (unsigned int)f2b(a.x) | ((unsigned int)f2b(a.y) << 16);
  r.y = (unsigned int)f2b(a.z) | ((unsigned int)f2b(a.w) << 16);
  r.z = (unsigned int)f2b(b.x) | ((unsigned int)f2b(b.y) << 16);
  r.w = (unsigned int)f2b(b.z) | ((unsigned int)f2b(b.w) << 16);
  return r;
}

// async global->LDS, 16B per lane
#define GLL(g, l) __builtin_amdgcn_global_load_lds( \
    (const __attribute__((address_space(1))) unsigned int*)(g), \
    (__attribute__((address_space(3))) unsigned int*)(l), 16, 0, 0)

// XCD-bijective blockIdx swizzle (T1, m204). Requires nwg % 8 == 0.
__device__ __forceinline__ void xcd_swz(int& bx, int& by, int& bz) {
  const int nx = gridDim.x, ny = gridDim.y;
  const int nwg = nx * ny * gridDim.z;
  const int lbid = blockIdx.x + nx * (blockIdx.y + ny * blockIdx.z);
  const int s = (lbid & 7) * (nwg >> 3) + (lbid >> 3);
  bx = s % nx; by = (s / nx) % ny; bz = s / (nx * ny);
}

// ---------------------------------------------------------------------------
// 256x256-tile 8-wave K-loop (catalog regime: per-wave 128x64 output).
// Rationale: 5 prior structural variants (occ 22-46%, prefetch 0-3, conflicts
// 2-5M) ALL landed 73-86us at ~8% MfmaUtil -- the invariant was FLOP per
// barrier-synced step (8-16 MFMA/wave). This structure does 32 MFMA/wave/step
// (acc[8][4]), 42.7 FLOP per LDS byte, counted vmcnt(4) (never drain in loop),
// raw barriers, setprio around the MFMA cluster.
// 512 threads = 8 waves in 2(M)x4(N); BK=32; LDS = dbuf 2 x (A 16KB + B 16KB)
// = 64 KB; 1 block/CU, 8 waves (occupancy ~25% BY DESIGN).
// Staging: 4 GLL/thread/step; thread covers rows tid>>2 and tid>>2+128 at
// k-chunk (tid&3)*8; LDS dest = tid*8 shorts (wave-uniform + lane*16B).
// ---------------------------------------------------------------------------
__device__ __forceinline__ void kloop256(const unsigned short* __restrict__ A,
                                         const unsigned short* __restrict__ B,
                                         int K, unsigned short* ldsA, unsigned short* ldsB,
                                         floatx4 (&acc)[8][4])
{
  const int tid = threadIdx.x;
  const int w = tid >> 6, lane = tid & 63;
  const int quad = lane >> 4, l16 = lane & 15;
  const int wr = w >> 2, wc = w & 3;           // wave grid 2M x 4N
  const int srow = tid >> 2;                   // staging row (0..127; +128 for 2nd)
  const int ks = (tid & 3) * 8;                // staging k-chunk (shorts)
  const int ldst = tid * 8;                    // LDS dest (shorts), tile-linear
  const unsigned short* gA0 = A + (size_t)srow * K + ks;
  const unsigned short* gA1 = gA0 + (size_t)128 * K;
  const unsigned short* gB0 = B + (size_t)srow * K + ks;
  const unsigned short* gB1 = gB0 + (size_t)128 * K;
  const int NT = K >> 5;

  // prologue: stage tile 0 into buf 0 (4 loads in flight, no drain)
  GLL(gA0, &ldsA[ldst]);
  GLL(gA1, &ldsA[4096 + ldst]);
  GLL(gB0, &ldsB[ldst]);
  GLL(gB1, &ldsB[4096 + ldst]);

  int cur = 0;
  for (int t = 0; t < NT; ++t) {
    const int nb = cur ^ 8192;
    if (t + 1 < NT) {
      const int k0 = (t + 1) * 32;
      GLL(gA0 + k0, &ldsA[nb + ldst]);
      GLL(gA1 + k0, &ldsA[nb + 4096 + ldst]);
      GLL(gB0 + k0, &ldsB[nb + ldst]);
      GLL(gB1 + k0, &ldsB[nb + 4096 + ldst]);
      asm volatile("s_waitcnt vmcnt(4)" ::: "memory");  // tile t landed; t+1 in flight
    } else {
      asm volatile("s_waitcnt vmcnt(0)" ::: "memory");  // tail drain
    }
    __builtin_amdgcn_s_barrier();            // all waves: tile t ready in buf[cur]
    __builtin_amdgcn_sched_barrier(0);
    short8 af[8], bf[4];
#pragma unroll
    for (int i = 0; i < 8; i++)
      af[i] = *(const short8*)&ldsA[cur + (wr * 128 + i * 16 + l16) * 32 + quad * 8];
#pragma unroll
    for (int j = 0; j < 4; j++)
      bf[j] = *(const short8*)&ldsB[cur + (wc * 64 + j * 16 + l16) * 32 + quad * 8];
    __builtin_amdgcn_s_setprio(1);
#pragma unroll
    for (int i = 0; i < 8; i++)
#pragma unroll
      for (int j = 0; j < 4; j++)
        acc[i][j] = __builtin_amdgcn_mfma_f32_16x16x32_bf16(af[i], bf[j], acc[i][j], 0, 0, 0);
    __builtin_amdgcn_s_setprio(0);
    __builtin_amdgcn_s_barrier();            // buf[cur] reads done -> overwritable
    __builtin_amdgcn_sched_barrier(0);
    cur = nb;
  }
}

#define ACC_INIT floatx4 acc[8][4]; \
  _Pragma("unroll") for (int i = 0; i < 8; i++) \
  _Pragma("unroll") for (int j = 0; j < 4; j++) acc[i][j] = (floatx4){0.f, 0.f, 0.f, 0.f};

// ---- fused QKV: C[16384,1536] split into q/k/v [16384,512] each
__global__ __launch_bounds__(512, 2) void gemm_qkv(
    const unsigned short* __restrict__ x,   // [16384,512] bf16
    const unsigned short* __restrict__ WT,  // [1536,512] bf16 (Wq^T;Wk^T;Wv^T)
    const float* __restrict__ bq, const float* __restrict__ bk, const float* __restrict__ bv,
    unsigned short* __restrict__ q, unsigned short* __restrict__ kx, unsigned short* __restrict__ v)
{
  __shared__ unsigned short ldsA[16384], ldsB[16384];
  int bx, by, bz;
  xcd_swz(bx, by, bz);
  const int m0 = by * 256, n0 = bx * 256;
  ACC_INIT
  kloop256(x + (size_t)m0 * 512, WT + (size_t)n0 * 512, 512, ldsA, ldsB, acc);

  const int seg = n0 >> 9, nloc = n0 & 511;   // 256-tile lies in one 512 segment
  unsigned short* C = seg == 0 ? q : (seg == 1 ? kx : v);
  const float* bias = seg == 0 ? bq : (seg == 1 ? bk : bv);
  const int lane = threadIdx.x & 63, w = threadIdx.x >> 6;
  const int quad = lane >> 4, l16 = lane & 15, wr = w >> 2, wc = w & 3;
  float bvv[4];
#pragma unroll
  for (int j = 0; j < 4; j++) bvv[j] = bias[nloc + wc * 64 + j * 16 + l16];
#pragma unroll
  for (int i = 0; i < 8; i++)
#pragma unroll
    for (int r = 0; r < 4; r++) {
      int m = m0 + wr * 128 + i * 16 + quad * 4 + r;
      unsigned short* crow = C + (size_t)m * 512 + nloc + wc * 64 + l16;
#pragma unroll
      for (int j = 0; j < 4; j++) crow[j * 16] = f2b(acc[i][j][r] + bvv[j]);
    }
}

// ---- generic bf16 GEMM: C = act(A @ Bt^T + bias), C fp32 (CF32) or bf16
template<int CF32, int ACT>
__global__ __launch_bounds__(512, 2) void gemm2(
    const unsigned short* __restrict__ A, const unsigned short* __restrict__ Bt,
    const float* __restrict__ bias, void* __restrict__ Cv,
    int N, int K, long aB, long bB, long cB)
{
  __shared__ unsigned short ldsA[16384], ldsB[16384];
  int bx, by, bz;
  xcd_swz(bx, by, bz);
  const int b = bz;
  const int m0 = by * 256, n0 = bx * 256;
  ACC_INIT
  kloop256(A + (size_t)b * aB + (size_t)m0 * K, Bt + (size_t)b * bB + (size_t)n0 * K,
           K, ldsA, ldsB, acc);

  const int lane = threadIdx.x & 63, w = threadIdx.x >> 6;
  const int quad = lane >> 4, l16 = lane & 15, wr = w >> 2, wc = w & 3;
  float bvv[4];
#pragma unroll
  for (int j = 0; j < 4; j++)
    bvv[j] = bias ? bias[n0 + wc * 64 + j * 16 + l16] : 0.f;
  float*          Cf = (float*)Cv          + (size_t)b * cB;
  unsigned short* Ch = (unsigned short*)Cv + (size_t)b * cB;
#pragma unroll
  for (int i = 0; i < 8; i++)
#pragma unroll
    for (int r = 0; r < 4; r++) {
      int m = m0 + wr * 128 + i * 16 + quad * 4 + r;
      size_t base = (size_t)m * N + n0 + wc * 64 + l16;
#pragma unroll
      for (int j = 0; j < 4; j++) {
        float vv = acc[i][j][r] + bvv[j];
        if (ACT == 1) vv = tanhf(vv);
        if (CF32) Cf[base + j * 16] = vv;
        else      Ch[base + j * 16] = f2b(vv);
      }
    }
}

// ---- score: E = dep ? exp(clamp((q.k)*dept[dep])) : 0, fp32
// Epilogue straight from regs: dep load + exp + 4B store per element;
// 16-lane groups touch 64B-contiguous segments (coalesced). dept is a 256B
// table -> L1-resident after first touch; no LDS round-trip needed.
__global__ __launch_bounds__(512, 2) void score_kernel(
    const unsigned short* __restrict__ Q, const unsigned short* __restrict__ Km,
    const int* __restrict__ dep, const float* __restrict__ dept,
    float* __restrict__ E)
{
  __shared__ unsigned short ldsA[16384], ldsB[16384];
  int bx, by, bz;
  xcd_swz(bx, by, bz);
  const int b = bz;
  const int m0 = by * 256, n0 = bx * 256;
  ACC_INIT
  kloop256(Q + (size_t)b * (1024 * 512) + (size_t)m0 * 512,
           Km + (size_t)b * (1024 * 512) + (size_t)n0 * 512,
           512, ldsA, ldsB, acc);

  const int tid = threadIdx.x;
  const int lane = tid & 63, w = tid >> 6;
  const int quad = lane >> 4, l16 = lane & 15, wr = w >> 2, wc = w & 3;
  const int* depb = dep + (size_t)b * 1024 * 1024;
  float* Eb = E + (size_t)b * 1024 * 1024;
#pragma unroll
  for (int i = 0; i < 8; i++)
#pragma unroll
    for (int r = 0; r < 4; r++) {
      const int m = m0 + wr * 128 + i * 16 + quad * 4 + r;
      const int* dr = depb + (size_t)m * 1024 + n0 + wc * 64 + l16;
      float* er = Eb + (size_t)m * 1024 + n0 + wc * 64 + l16;
#pragma unroll
      for (int j = 0; j < 4; j++) {
        int d = dr[j * 16];
        float s = acc[i][j][r];
        er[j * 16] = d ? __expf(fminf(fmaxf(s * dept[d & 63], -60.f), 60.f)) : 0.f;
      }
    }
}

// ---- x = bf16(embed[inputs]) : one row per 64 lanes, 4 rows/block
__global__ void build_x(const float* __restrict__ embed, const int* __restrict__ inputs,
                        unsigned short* __restrict__ x)
{
  const int row = blockIdx.x * 4 + (threadIdx.x >> 6);
  const int lane = threadIdx.x & 63;
  const float* src = embed + (size_t)inputs[row] * 512 + lane * 8;
  *(uint4*)&x[(size_t)row * 512 + lane * 8] = ld8f(src);
}

// ---- all 5 weight transposes fp32->bf16 in one launch (z selects source)
__global__ void trans_w(const float* s0, const float* s1, const float* s2,
                        const float* s3, const float* s4, unsigned short* dst)
{
  __shared__ unsigned short tile[32][33];
  const int z = blockIdx.z;
  const float* src = z == 0 ? s0 : z == 1 ? s1 : z == 2 ? s2 : z == 3 ? s3 : s4;
  unsigned short* ob = dst + (size_t)z * 262144;
  int c0 = blockIdx.x * 32, r0 = blockIdx.y * 32;
  int tx = threadIdx.x & 31, ty = threadIdx.x >> 5;
  for (int i = ty; i < 32; i += 8)
    tile[i][tx] = f2b(src[(size_t)(r0 + i) * 512 + (c0 + tx)]);
  __syncthreads();
  for (int i = ty; i < 32; i += 8)
    ob[(size_t)(c0 + i) * 512 + (r0 + tx)] = tile[tx][i];
}

// ---- bf16 transpose (v -> vT), batched
__global__ void trans_v(const unsigned short* __restrict__ in, unsigned short* __restrict__ out)
{
  __shared__ unsigned short tile[32][33];
  const unsigned short* ib = in + (size_t)blockIdx.z * (1024 * 512);
  unsigned short* ob = out + (size_t)blockIdx.z * (512 * 1024);
  int c0 = blockIdx.x * 32, r0 = blockIdx.y * 32;
  int tx = threadIdx.x & 31, ty = threadIdx.x >> 5;
  for (int i = ty; i < 32; i += 8)
    tile[i][tx] = ib[(size_t)(r0 + i) * 512 + (c0 + tx)];
  __syncthreads();
  for (int i = ty; i < 32; i += 8)
    ob[(size_t)(c0 + i) * 1024 + (r0 + tx)] = tile[tx][i];
}

// ---- rows /= rowsum; also emit bf16 copy for the PV GEMM
__global__ void normalize_rows(float* __restrict__ wf, unsigned short* __restrict__ wb)
{
  size_t row = blockIdx.x;
  float4* p = (float4*)(wf + row * 1024);
  float4 u = p[threadIdx.x];
  float s = (u.x + u.y) + (u.z + u.w);
#pragma unroll
  for (int d = 1; d < 64; d <<= 1) s += __shfl_xor(s, d);
  __shared__ float acc4[4];
  if ((threadIdx.x & 63) == 0) acc4[threadIdx.x >> 6] = s;
  __syncthreads();
  float tot = (acc4[0] + acc4[1]) + (acc4[2] + acc4[3]);
  float inv = tot > 0.f ? 1.f / tot : 0.f;
  u.x *= inv; u.y *= inv; u.z *= inv; u.w *= inv;
  p[threadIdx.x] = u;
  uint2 pk;
  pk.x = (unsigned int)f2b(u.x) | ((unsigned int)f2b(u.y) << 16);
  pk.y = (unsigned int)f2b(u.z) | ((unsigned int)f2b(u.w) << 16);
  *(uint2*)&wb[row * 1024 + threadIdx.x * 4] = pk;
}

extern "C" void kernel_launch(void* const* d_in, const int* in_sizes, int n_in,
                              void* d_out, int out_size, void* d_ws, size_t ws_size,
                              hipStream_t stream)
{
  const int*   inputs     = (const int*)d_in[0];
  const int*   dependency = (const int*)d_in[1];
  const float* embed      = (const float*)d_in[2];
  const float* dept       = (const float*)d_in[3];
  const float* Wq = (const float*)d_in[4];   const float* bq = (const float*)d_in[5];
  const float* Wk = (const float*)d_in[6];   const float* bk = (const float*)d_in[7];
  const float* Wv = (const float*)d_in[8];   const float* bvv = (const float*)d_in[9];
  const float* W1 = (const float*)d_in[10];  const float* b1 = (const float*)d_in[11];
  const float* W2 = (const float*)d_in[12];  const float* b2 = (const float*)d_in[13];

  float* out  = (float*)d_out;                       // wm [16,1024,512] fp32 (32 MB)
  float* wout = out + (size_t)8388608;               // weights [16,1024,1024] fp32 (64 MB)

  // ws (shorts), high-water 36.2 MB:
  //  [0 .. 8388608)        q          -> wbf lo -> h
  //  [8388608 .. 16777216) kx         -> wbf hi
  //  [16777216 .. )        WTcat(3x) W1T W2T  (end 18087936)
  unsigned short* ws   = (unsigned short*)d_ws;
  unsigned short* q    = ws;
  unsigned short* kx   = ws + 8388608;
  unsigned short* WTc  = ws + 16777216;
  unsigned short* W1T  = ws + 17563648;
  unsigned short* W2T  = ws + 17825792;
  unsigned short* wbf  = ws;                          // [16384,1024] bf16 (32 MB)
  unsigned short* h    = ws;                          // [16384,512] bf16

  // output regions used as staging (dead before final writes):
  unsigned short* x    = (unsigned short*)wout;       // [16384,512] bf16; E overwrites later
  unsigned short* v    = (unsigned short*)out;        // [16384,512] bf16 in wm region lo
  unsigned short* vT   = (unsigned short*)out + 8388608;  // [16,512,1024] bf16 in wm hi
  unsigned short* wmp  = (unsigned short*)out;        // [16384,512] bf16 (over dead v)

  dim3 blk(256), blk5(512);

  trans_w<<<dim3(16, 16, 5), blk, 0, stream>>>(Wq, Wk, Wv, W1, W2, WTc);
  build_x<<<dim3(4096), blk, 0, stream>>>(embed, inputs, x);

  gemm_qkv<<<dim3(6, 64, 1), blk5, 0, stream>>>(x, WTc, bq, bk, bvv, q, kx, v);

  score_kernel<<<dim3(4, 4, 16), blk5, 0, stream>>>(q, kx, dependency, dept, wout);

  trans_v<<<dim3(16, 32, 16), blk, 0, stream>>>(v, vT);

  normalize_rows<<<dim3(16384), blk, 0, stream>>>(wout, wbf);

  // wm_pre = weights @ v   (bf16 x bf16, batched)
  gemm2<0, 0><<<dim3(2, 4, 16), blk5, 0, stream>>>(wbf, vT, nullptr, wmp,
                                                   512, 1024, 1024L * 1024, 512L * 1024, 1024L * 512);
  // h = tanh(wm_pre @ W1^T + b1)
  gemm2<0, 1><<<dim3(2, 64, 1), blk5, 0, stream>>>(wmp, W1T, b1, h, 512, 512, 0, 0, 0);
  // wm = h @ W2^T + b2  (fp32, overwrites wmp/vT staging -- both dead)
  gemm2<1, 0><<<dim3(2, 64, 1), blk5, 0, stream>>>(h, W2T, b2, out, 512, 512, 0, 0, 0);
}

// Round 8
// 438.673 us; speedup vs baseline: 1.1455x; 1.1455x over previous
//
#include <hip/hip_runtime.h>

typedef __attribute__((ext_vector_type(8))) short short8;
typedef __attribute__((ext_vector_type(4))) float floatx4;

__device__ __forceinline__ unsigned short f2b(float f) {
  unsigned int u = __float_as_uint(f);
  unsigned int r = (u + 0x7FFFu + ((u >> 16) & 1u)) >> 16;  // RNE
  return (unsigned short)r;
}
__device__ __forceinline__ unsigned int pk2(float a, float b) {
  return (unsigned int)f2b(a) | ((unsigned int)f2b(b) << 16);
}
// pack 8 fp32 (two float4) -> 8 bf16 in a uint4
__device__ __forceinline__ uint4 pack8(float4 a, float4 b) {
  uint4 r;
  r.x = pk2(a.x, a.y); r.y = pk2(a.z, a.w);
  r.z = pk2(b.x, b.y); r.w = pk2(b.z, b.w);
  return r;
}

// XCD-bijective swizzle over the 2D (bx,by) grid only: keeps each XCD's L2
// working set within ONE batch (score: ~1.3MB vs 4MB borderline with 3D).
// Requires nx*ny % 8 == 0 (qkv 3072, score 128, PV 64, W1/W2 1024: all ok).
__device__ __forceinline__ void xcd_swz2(int& bx, int& by) {
  const int nx = gridDim.x, ny = gridDim.y;
  const int nwg = nx * ny;
  const int lbid = blockIdx.x + nx * blockIdx.y;
  const int s = (lbid & 7) * (nwg >> 3) + (lbid >> 3);
  bx = s % nx; by = s / nx;
}

// ---------------------------------------------------------------------------
// Reg-staged double-buffered K-loop, BK=64 (r5 structure, steps halved).
// Rationale: r0-r5 structural variants all latency-pinned per barrier-step
// (~750-1500cy vs ~300cy compute); r6 showed fewer blocks only hurts. So at
// FIXED tile(64x128)/grid, double FLOP per step: NT=K/64, 16 MFMA/wave/step,
// 12 ds_read_b128/step, 6 (or 8 w/ embed) global loads issued at step start,
// converted/written to the other LDS buffer at step end (wave-local vmcnt
// wait rides under this step's MFMA). One raw s_barrier per step, lgkmcnt(0)
// only; no vmem drain in-loop. LDS: 2 x (A 8KB + B 16KB) = 48KB -> 3 blk/CU.
// Safety: reads of buf[p] are lgkm-drained before each wave's barrier; the
// in-step ds_writes touch only buf[p^1]. sched_barrier(0) fences hoisting.
// EMB variant: A-operand gathered from embed[inputs[row]] fp32 and packed to
// bf16 at write time (load fp32 early, convert late) -- kills build_x + x buf.
// ---------------------------------------------------------------------------
template<bool EMB>
__device__ __forceinline__ void kloop64(const unsigned short* __restrict__ A,
                                        const float* __restrict__ emb,
                                        const int* __restrict__ inpRow,
                                        const unsigned short* __restrict__ B,
                                        int K, unsigned short* ldsA, unsigned short* ldsB,
                                        floatx4 (&acc)[2][4])
{
  const int tid = threadIdx.x;
  const int w = tid >> 6, lane = tid & 63;
  const int quad = lane >> 4, l16 = lane & 15;
  const int wy = w >> 1, wx = w & 1;
  const int row = tid >> 2;                  // staging row 0..63
  const int kc = (tid & 3) * 8;              // k-chunk (shorts): 0,8,16,24 (+32)
  const int loa  = row * 64 + kc;            // LDS A dest (tile [64][64] shorts)
  const int lob0 = row * 64 + kc;            // LDS B dest rows 0..63
  const int lob1 = lob0 + 4096;              // rows 64..127
  const unsigned short* ga  = A + (size_t)row * K + kc;
  const float*          gaf = EMB ? emb + (size_t)inpRow[row] * 512 + kc : nullptr;
  const unsigned short* gb0 = B + (size_t)row * K + kc;
  const unsigned short* gb1 = gb0 + (size_t)64 * K;
  const int NT = K >> 6;

  uint4 va0, va1, vb00, vb01, vb10, vb11;
  float4 fa0, fa1, fa2, fa3;

  // prologue: tile 0 -> regs -> buf0
  if (EMB) {
    fa0 = *(const float4*)(gaf);      fa1 = *(const float4*)(gaf + 4);
    fa2 = *(const float4*)(gaf + 32); fa3 = *(const float4*)(gaf + 36);
    va0 = pack8(fa0, fa1); va1 = pack8(fa2, fa3);
  } else {
    va0 = *(const uint4*)ga; va1 = *(const uint4*)(ga + 32);
  }
  vb00 = *(const uint4*)gb0; vb01 = *(const uint4*)(gb0 + 32);
  vb10 = *(const uint4*)gb1; vb11 = *(const uint4*)(gb1 + 32);
  *(uint4*)&ldsA[loa] = va0;       *(uint4*)&ldsA[loa + 32] = va1;
  *(uint4*)&ldsB[lob0] = vb00;     *(uint4*)&ldsB[lob0 + 32] = vb01;
  *(uint4*)&ldsB[lob1] = vb10;     *(uint4*)&ldsB[lob1 + 32] = vb11;
  asm volatile("s_waitcnt lgkmcnt(0)" ::: "memory");
  __builtin_amdgcn_s_barrier();
  __builtin_amdgcn_sched_barrier(0);

  int p = 0;
  for (int t = 0; t < NT; ++t) {
    // issue next tile's global loads NOW (convert later, at write time)
    if (t + 1 < NT) {
      const int k0 = (t + 1) * 64;
      if (EMB) {
        fa0 = *(const float4*)(gaf + k0);      fa1 = *(const float4*)(gaf + k0 + 4);
        fa2 = *(const float4*)(gaf + k0 + 32); fa3 = *(const float4*)(gaf + k0 + 36);
      } else {
        va0 = *(const uint4*)(ga + k0); va1 = *(const uint4*)(ga + k0 + 32);
      }
      vb00 = *(const uint4*)(gb0 + k0); vb01 = *(const uint4*)(gb0 + k0 + 32);
      vb10 = *(const uint4*)(gb1 + k0); vb11 = *(const uint4*)(gb1 + k0 + 32);
    }
    const int ca = p ? 4096 : 0, cb = p ? 8192 : 0;
    short8 af[2][2], bf[2][4];
#pragma unroll
    for (int s = 0; s < 2; s++) {
#pragma unroll
      for (int i = 0; i < 2; i++)
        af[s][i] = *(const short8*)&ldsA[ca + (wy * 32 + i * 16 + l16) * 64 + s * 32 + quad * 8];
#pragma unroll
      for (int j = 0; j < 4; j++)
        bf[s][j] = *(const short8*)&ldsB[cb + (wx * 64 + j * 16 + l16) * 64 + s * 32 + quad * 8];
    }
#pragma unroll
    for (int s = 0; s < 2; s++)
#pragma unroll
      for (int i = 0; i < 2; i++)
#pragma unroll
        for (int j = 0; j < 4; j++)
          acc[i][j] = __builtin_amdgcn_mfma_f32_16x16x32_bf16(af[s][i], bf[s][j], acc[i][j], 0, 0, 0);
    if (t + 1 < NT) {
      const int na = p ? 0 : 4096, nb = p ? 0 : 8192;
      if (EMB) { va0 = pack8(fa0, fa1); va1 = pack8(fa2, fa3); }
      *(uint4*)&ldsA[na + loa] = va0;    *(uint4*)&ldsA[na + loa + 32] = va1;
      *(uint4*)&ldsB[nb + lob0] = vb00;  *(uint4*)&ldsB[nb + lob0 + 32] = vb01;
      *(uint4*)&ldsB[nb + lob1] = vb10;  *(uint4*)&ldsB[nb + lob1 + 32] = vb11;
    }
    asm volatile("s_waitcnt lgkmcnt(0)" ::: "memory");
    __builtin_amdgcn_s_barrier();
    __builtin_amdgcn_sched_barrier(0);
    p ^= 1;
  }
}

// ---- fused QKV + embedding gather: C[16384,1536] -> q/k/v [16384,512] each
__global__ __launch_bounds__(256, 3) void gemm_qkv(
    const float* __restrict__ embed,        // [32000,512] fp32
    const int* __restrict__ inputs,         // [16384]
    const unsigned short* __restrict__ WT,  // [1536,512] bf16 (Wq^T;Wk^T;Wv^T)
    const float* __restrict__ bq, const float* __restrict__ bk, const float* __restrict__ bv,
    unsigned short* __restrict__ q, unsigned short* __restrict__ kx, unsigned short* __restrict__ v)
{
  __shared__ unsigned short ldsA[8192], ldsB[16384];
  int bx, by;
  xcd_swz2(bx, by);
  const int m0 = by * 64, n0 = bx * 128;
  floatx4 acc[2][4];
#pragma unroll
  for (int i = 0; i < 2; i++)
#pragma unroll
    for (int j = 0; j < 4; j++) acc[i][j] = (floatx4){0.f, 0.f, 0.f, 0.f};

  kloop64<true>(nullptr, embed, inputs + m0, WT + (size_t)n0 * 512, 512, ldsA, ldsB, acc);

  const int seg = n0 >> 9, nloc = n0 & 511;
  unsigned short* C = seg == 0 ? q : (seg == 1 ? kx : v);
  const float* bias = seg == 0 ? bq : (seg == 1 ? bk : bv);
  const int lane = threadIdx.x & 63, w = threadIdx.x >> 6;
  const int quad = lane >> 4, l16 = lane & 15, wy = w >> 1, wx = w & 1;
  float bvv[4];
#pragma unroll
  for (int j = 0; j < 4; j++) bvv[j] = bias[nloc + wx * 64 + j * 16 + l16];
#pragma unroll
  for (int i = 0; i < 2; i++)
#pragma unroll
    for (int r = 0; r < 4; r++) {
      int m = m0 + wy * 32 + i * 16 + quad * 4 + r;
      unsigned short* crow = C + (size_t)m * 512 + nloc + wx * 64 + l16;
#pragma unroll
      for (int j = 0; j < 4; j++) crow[j * 16] = f2b(acc[i][j][r] + bvv[j]);
    }
}

// ---- generic bf16 GEMM: C = act(A @ Bt^T + bias), C fp32 (CF32) or bf16
template<int CF32, int ACT>
__global__ __launch_bounds__(256, 3) void gemm2(
    const unsigned short* __restrict__ A, const unsigned short* __restrict__ Bt,
    const float* __restrict__ bias, void* __restrict__ Cv,
    int N, int K, long aB, long bB, long cB)
{
  __shared__ unsigned short ldsA[8192], ldsB[16384];
  int bx, by;
  xcd_swz2(bx, by);
  const int b = blockIdx.z;
  const int m0 = by * 64, n0 = bx * 128;
  floatx4 acc[2][4];
#pragma unroll
  for (int i = 0; i < 2; i++)
#pragma unroll
    for (int j = 0; j < 4; j++) acc[i][j] = (floatx4){0.f, 0.f, 0.f, 0.f};

  kloop64<false>(A + (size_t)b * aB + (size_t)m0 * K, nullptr, nullptr,
                 Bt + (size_t)b * bB + (size_t)n0 * K, K, ldsA, ldsB, acc);

  const int lane = threadIdx.x & 63, w = threadIdx.x >> 6;
  const int quad = lane >> 4, l16 = lane & 15, wy = w >> 1, wx = w & 1;
  float bvv[4];
#pragma unroll
  for (int j = 0; j < 4; j++)
    bvv[j] = bias ? bias[n0 + wx * 64 + j * 16 + l16] : 0.f;
  float*          Cf = (float*)Cv          + (size_t)b * cB;
  unsigned short* Ch = (unsigned short*)Cv + (size_t)b * cB;
#pragma unroll
  for (int i = 0; i < 2; i++)
#pragma unroll
    for (int r = 0; r < 4; r++) {
      int m = m0 + wy * 32 + i * 16 + quad * 4 + r;
      size_t base = (size_t)m * N + n0 + wx * 64 + l16;
#pragma unroll
      for (int j = 0; j < 4; j++) {
        float vv = acc[i][j][r] + bvv[j];
        if (ACT == 1) vv = tanhf(vv);
        if (CF32) Cf[base + j * 16] = vv;
        else      Ch[base + j * 16] = f2b(vv);
      }
    }
}

// ---- score: E = dep ? exp(clamp((q.k)*dtab[dep])) : 0, fp32, coalesced epilogue
#define CST 132  // padded fp32 tile stride (floats): breaks row-bank aliasing
__global__ __launch_bounds__(256, 3) void score_kernel(
    const unsigned short* __restrict__ Q, const unsigned short* __restrict__ Km,
    const int* __restrict__ dep, const float* __restrict__ dept,
    float* __restrict__ E)
{
  __shared__ union {
    struct { unsigned short a[8192]; unsigned short b[16384]; } s;
    float c[32 * CST];
  } sm;
  __shared__ float dtab[64];
  const int tid = threadIdx.x;
  if (tid < 64) dtab[tid] = dept[tid];

  int bx, by;
  xcd_swz2(bx, by);
  const int b = blockIdx.z;
  const int m0 = by * 64, n0 = bx * 128;
  floatx4 acc[2][4];
#pragma unroll
  for (int i = 0; i < 2; i++)
#pragma unroll
    for (int j = 0; j < 4; j++) acc[i][j] = (floatx4){0.f, 0.f, 0.f, 0.f};

  kloop64<false>(Q + (size_t)b * (1024 * 512) + (size_t)m0 * 512, nullptr, nullptr,
                 Km + (size_t)b * (1024 * 512) + (size_t)n0 * 512, 512, sm.s.a, sm.s.b, acc);

  const int lane = tid & 63, w = tid >> 6;
  const int quad = lane >> 4, l16 = lane & 15, wy = w >> 1, wx = w & 1;
  const int* depb = dep + (size_t)b * 1024 * 1024;
  float* Eb = E + (size_t)b * 1024 * 1024;
  const int cr = tid >> 3, cb = (tid & 7) * 16;

#pragma unroll
  for (int i = 0; i < 2; i++) {
    __syncthreads();  // LDS free (kloop done / prior i's tile reads done)
#pragma unroll
    for (int j = 0; j < 4; j++)
#pragma unroll
      for (int r = 0; r < 4; r++)
        sm.c[(wy * 16 + quad * 4 + r) * CST + wx * 64 + j * 16 + l16] = acc[i][j][r];
    __syncthreads();
    // 32 rows x 128 cols; thread: row cr, 16 cols at cb -- all 16B accesses
    const int m = m0 + (cr >> 4) * 32 + i * 16 + (cr & 15);
    const int* dr = depb + (size_t)m * 1024 + n0 + cb;
    float* er = Eb + (size_t)m * 1024 + n0 + cb;
    const float* crow = &sm.c[cr * CST + cb];
#pragma unroll
    for (int c = 0; c < 4; c++) {
      int4 d = *(const int4*)(dr + c * 4);
      float4 s = *(const float4*)(crow + c * 4);
      float4 e;
      e.x = d.x ? __expf(fminf(fmaxf(s.x * dtab[d.x & 63], -60.f), 60.f)) : 0.f;
      e.y = d.y ? __expf(fminf(fmaxf(s.y * dtab[d.y & 63], -60.f), 60.f)) : 0.f;
      e.z = d.z ? __expf(fminf(fmaxf(s.z * dtab[d.z & 63], -60.f), 60.f)) : 0.f;
      e.w = d.w ? __expf(fminf(fmaxf(s.w * dtab[d.w & 63], -60.f), 60.f)) : 0.f;
      *(float4*)(er + c * 4) = e;
    }
  }
}

// ---- all 5 weight transposes fp32->bf16 in one launch (z selects source)
__global__ void trans_w(const float* s0, const float* s1, const float* s2,
                        const float* s3, const float* s4, unsigned short* dst)
{
  __shared__ unsigned short tile[32][33];
  const int z = blockIdx.z;
  const float* src = z == 0 ? s0 : z == 1 ? s1 : z == 2 ? s2 : z == 3 ? s3 : s4;
  unsigned short* ob = dst + (size_t)z * 262144;
  int c0 = blockIdx.x * 32, r0 = blockIdx.y * 32;
  int tx = threadIdx.x & 31, ty = threadIdx.x >> 5;
  for (int i = ty; i < 32; i += 8)
    tile[i][tx] = f2b(src[(size_t)(r0 + i) * 512 + (c0 + tx)]);
  __syncthreads();
  for (int i = ty; i < 32; i += 8)
    ob[(size_t)(c0 + i) * 512 + (r0 + tx)] = tile[tx][i];
}

// ---- bf16 transpose (v -> vT), batched
__global__ void trans_v(const unsigned short* __restrict__ in, unsigned short* __restrict__ out)
{
  __shared__ unsigned short tile[32][33];
  const unsigned short* ib = in + (size_t)blockIdx.z * (1024 * 512);
  unsigned short* ob = out + (size_t)blockIdx.z * (512 * 1024);
  int c0 = blockIdx.x * 32, r0 = blockIdx.y * 32;
  int tx = threadIdx.x & 31, ty = threadIdx.x >> 5;
  for (int i = ty; i < 32; i += 8)
    tile[i][tx] = ib[(size_t)(r0 + i) * 512 + (c0 + tx)];
  __syncthreads();
  for (int i = ty; i < 32; i += 8)
    ob[(size_t)(c0 + i) * 1024 + (r0 + tx)] = tile[tx][i];
}

// ---- rows /= rowsum; also emit bf16 copy for the PV GEMM
__global__ void normalize_rows(float* __restrict__ wf, unsigned short* __restrict__ wb)
{
  size_t row = blockIdx.x;
  float4* p = (float4*)(wf + row * 1024);
  float4 u = p[threadIdx.x];
  float s = (u.x + u.y) + (u.z + u.w);
#pragma unroll
  for (int d = 1; d < 64; d <<= 1) s += __shfl_xor(s, d);
  __shared__ float acc4[4];
  if ((threadIdx.x & 63) == 0) acc4[threadIdx.x >> 6] = s;
  __syncthreads();
  float tot = (acc4[0] + acc4[1]) + (acc4[2] + acc4[3]);
  float inv = tot > 0.f ? 1.f / tot : 0.f;
  u.x *= inv; u.y *= inv; u.z *= inv; u.w *= inv;
  p[threadIdx.x] = u;
  uint2 pk;
  pk.x = pk2(u.x, u.y);
  pk.y = pk2(u.z, u.w);
  *(uint2*)&wb[row * 1024 + threadIdx.x * 4] = pk;
}

extern "C" void kernel_launch(void* const* d_in, const int* in_sizes, int n_in,
                              void* d_out, int out_size, void* d_ws, size_t ws_size,
                              hipStream_t stream)
{
  const int*   inputs     = (const int*)d_in[0];
  const int*   dependency = (const int*)d_in[1];
  const float* embed      = (const float*)d_in[2];
  const float* dept       = (const float*)d_in[3];
  const float* Wq = (const float*)d_in[4];   const float* bq = (const float*)d_in[5];
  const float* Wk = (const float*)d_in[6];   const float* bk = (const float*)d_in[7];
  const float* Wv = (const float*)d_in[8];   const float* bvv = (const float*)d_in[9];
  const float* W1 = (const float*)d_in[10];  const float* b1 = (const float*)d_in[11];
  const float* W2 = (const float*)d_in[12];  const float* b2 = (const float*)d_in[13];

  float* out  = (float*)d_out;                       // wm [16,1024,512] fp32 (32 MB)
  float* wout = out + (size_t)8388608;               // weights [16,1024,1024] fp32 (64 MB)

  // ws (shorts):
  //  [0 .. 8388608)        q          -> wbf lo -> h
  //  [8388608 .. 16777216) kx         -> wbf hi
  //  [16777216 .. )        WTcat(3x) W1T W2T  (end 18087936)
  unsigned short* ws   = (unsigned short*)d_ws;
  unsigned short* q    = ws;
  unsigned short* kx   = ws + 8388608;
  unsigned short* WTc  = ws + 16777216;
  unsigned short* W1T  = ws + 17563648;
  unsigned short* W2T  = ws + 17825792;
  unsigned short* wbf  = ws;                          // [16384,1024] bf16 (32 MB)
  unsigned short* h    = ws;                          // [16384,512] bf16

  // output regions used as staging (dead before final writes):
  unsigned short* v    = (unsigned short*)out;        // [16384,512] bf16 in wm region lo
  unsigned short* vT   = (unsigned short*)out + 8388608;  // [16,512,1024] bf16 in wm hi
  unsigned short* wmp  = (unsigned short*)out;        // [16384,512] bf16 (over dead v)

  dim3 blk(256);

  trans_w<<<dim3(16, 16, 5), blk, 0, stream>>>(Wq, Wk, Wv, W1, W2, WTc);

  // embed gather fused into the A-staging (build_x eliminated)
  gemm_qkv<<<dim3(12, 256, 1), blk, 0, stream>>>(embed, inputs, WTc, bq, bk, bvv, q, kx, v);

  score_kernel<<<dim3(8, 16, 16), blk, 0, stream>>>(q, kx, dependency, dept, wout);

  trans_v<<<dim3(16, 32, 16), blk, 0, stream>>>(v, vT);

  normalize_rows<<<dim3(16384), blk, 0, stream>>>(wout, wbf);

  // wm_pre = weights @ v   (bf16 x bf16, batched)
  gemm2<0, 0><<<dim3(4, 16, 16), blk, 0, stream>>>(wbf, vT, nullptr, wmp,
                                                   512, 1024, 1024L * 1024, 512L * 1024, 1024L * 512);
  // h = tanh(wm_pre @ W1^T + b1)
  gemm2<0, 1><<<dim3(4, 256, 1), blk, 0, stream>>>(wmp, W1T, b1, h, 512, 512, 0, 0, 0);
  // wm = h @ W2^T + b2  (fp32, overwrites wmp/vT staging -- both dead)
  gemm2<1, 0><<<dim3(4, 256, 1), blk, 0, stream>>>(h, W2T, b2, out, 512, 512, 0, 0, 0);
}

// Round 9
// 413.179 us; speedup vs baseline: 1.2162x; 1.0617x over previous
//
#include <hip/hip_runtime.h>

typedef __attribute__((ext_vector_type(8))) short short8;
typedef __attribute__((ext_vector_type(4))) float floatx4;

__device__ __forceinline__ unsigned short f2b(float f) {
  unsigned int u = __float_as_uint(f);
  unsigned int r = (u + 0x7FFFu + ((u >> 16) & 1u)) >> 16;  // RNE
  return (unsigned short)r;
}
__device__ __forceinline__ unsigned int pk2(float a, float b) {
  return (unsigned int)f2b(a) | ((unsigned int)f2b(b) << 16);
}
// pack 8 fp32 (two float4) -> 8 bf16 in a uint4
__device__ __forceinline__ uint4 pack8(float4 a, float4 b) {
  uint4 r;
  r.x = pk2(a.x, a.y); r.y = pk2(a.z, a.w);
  r.z = pk2(b.x, b.y); r.w = pk2(b.z, b.w);
  return r;
}

// XCD-bijective swizzle over the 2D (bx,by) grid only. Requires nx*ny % 8 == 0.
__device__ __forceinline__ void xcd_swz2(int& bx, int& by) {
  const int nx = gridDim.x, ny = gridDim.y;
  const int nwg = nx * ny;
  const int lbid = blockIdx.x + nx * blockIdx.y;
  const int s = (lbid & 7) * (nwg >> 3) + (lbid >> 3);
  bx = s % nx; by = s / nx;
}

// ---------------------------------------------------------------------------
// Reg-staged double-buffered K-loop, BK=64, CONFLICT-SAFE LDS LAYOUT.
// r8 lesson (counters): stride-128B LDS rows = 16-way bank conflict on both
// ds_write and ds_read (conflicts 5.2M->18.9M, qkv 90us). Fix: store each
// 64-k tile as TWO [rows][32-short] subtiles (stride 64B, the r0-r5 layout):
//   A buf = [2 sub][64][32] (4096 shorts); B buf = [2 sub][128][32] (8192).
// Staging dest per subtile is linear tid*8 (== (tid>>2)*32+(tid&3)*8) ->
// conflict-free writes; reads are the known 8-way (r0-r5 baseline).
// Schedule per step (8 steps at K=512): issue 6 (8 w/EMB) global loads ->
// 12 ds_read_b128 -> 16 MFMA -> 6 ds_write_b128 to other buf (wave-local
// vmcnt wait rides under the MFMAs) -> lgkmcnt(0) -> raw s_barrier.
// No vmem drain in-loop. LDS 48KB -> 3 blk/CU.
// Safety: reads of buf[p] lgkm-drained before each wave's own barrier;
// in-step writes touch only buf[p^1]. sched_barrier(0) fences hoisting.
// EMB: A gathered from embed[inputs[row]] fp32, packed bf16 at write time.
// ---------------------------------------------------------------------------
template<bool EMB>
__device__ __forceinline__ void kloop64(const unsigned short* __restrict__ A,
                                        const float* __restrict__ emb,
                                        const int* __restrict__ inpRow,
                                        const unsigned short* __restrict__ B,
                                        int K, unsigned short* ldsA, unsigned short* ldsB,
                                        floatx4 (&acc)[2][4])
{
  const int tid = threadIdx.x;
  const int w = tid >> 6, lane = tid & 63;
  const int quad = lane >> 4, l16 = lane & 15;
  const int wy = w >> 1, wx = w & 1;
  const int row = tid >> 2;                  // staging row 0..63
  const int kc = (tid & 3) * 8;              // chunk within a 32-k subtile
  const int ld0 = tid * 8;                   // linear dest inside a [64][32] subtile
  const unsigned short* ga  = A + (size_t)row * K + kc;
  const float*          gaf = EMB ? emb + (size_t)inpRow[row] * 512 + kc : nullptr;
  const unsigned short* gb0 = B + (size_t)row * K + kc;
  const unsigned short* gb1 = gb0 + (size_t)64 * K;
  const int NT = K >> 6;

  uint4 va0, va1, vb00, vb01, vb10, vb11;
  float4 fa0, fa1, fa2, fa3;

  // prologue: tile 0 -> regs -> buf0
  if (EMB) {
    fa0 = *(const float4*)(gaf);      fa1 = *(const float4*)(gaf + 4);
    fa2 = *(const float4*)(gaf + 32); fa3 = *(const float4*)(gaf + 36);
    va0 = pack8(fa0, fa1); va1 = pack8(fa2, fa3);
  } else {
    va0 = *(const uint4*)ga; va1 = *(const uint4*)(ga + 32);
  }
  vb00 = *(const uint4*)gb0; vb01 = *(const uint4*)(gb0 + 32);
  vb10 = *(const uint4*)gb1; vb11 = *(const uint4*)(gb1 + 32);
  // A: sub0 @0, sub1 @2048. B: sub0 rows0-63 @0, rows64-127 @2048; sub1 @4096/+6144.
  *(uint4*)&ldsA[ld0] = va0;          *(uint4*)&ldsA[2048 + ld0] = va1;
  *(uint4*)&ldsB[ld0] = vb00;         *(uint4*)&ldsB[4096 + ld0] = vb01;
  *(uint4*)&ldsB[2048 + ld0] = vb10;  *(uint4*)&ldsB[6144 + ld0] = vb11;
  asm volatile("s_waitcnt lgkmcnt(0)" ::: "memory");
  __builtin_amdgcn_s_barrier();
  __builtin_amdgcn_sched_barrier(0);

  int p = 0;
  for (int t = 0; t < NT; ++t) {
    // issue next tile's global loads NOW (convert later, at write time)
    if (t + 1 < NT) {
      const int k0 = (t + 1) * 64;
      if (EMB) {
        fa0 = *(const float4*)(gaf + k0);      fa1 = *(const float4*)(gaf + k0 + 4);
        fa2 = *(const float4*)(gaf + k0 + 32); fa3 = *(const float4*)(gaf + k0 + 36);
      } else {
        va0 = *(const uint4*)(ga + k0); va1 = *(const uint4*)(ga + k0 + 32);
      }
      vb00 = *(const uint4*)(gb0 + k0); vb01 = *(const uint4*)(gb0 + k0 + 32);
      vb10 = *(const uint4*)(gb1 + k0); vb11 = *(const uint4*)(gb1 + k0 + 32);
    }
    const int ca = p ? 4096 : 0, cb = p ? 8192 : 0;
    short8 af[2][2], bf[2][4];
#pragma unroll
    for (int s = 0; s < 2; s++) {
#pragma unroll
      for (int i = 0; i < 2; i++)
        af[s][i] = *(const short8*)&ldsA[ca + s * 2048 + (wy * 32 + i * 16 + l16) * 32 + quad * 8];
#pragma unroll
      for (int j = 0; j < 4; j++)
        bf[s][j] = *(const short8*)&ldsB[cb + s * 4096 + (wx * 64 + j * 16 + l16) * 32 + quad * 8];
    }
#pragma unroll
    for (int s = 0; s < 2; s++)
#pragma unroll
      for (int i = 0; i < 2; i++)
#pragma unroll
        for (int j = 0; j < 4; j++)
          acc[i][j] = __builtin_amdgcn_mfma_f32_16x16x32_bf16(af[s][i], bf[s][j], acc[i][j], 0, 0, 0);
    if (t + 1 < NT) {
      const int na = p ? 0 : 4096, nb = p ? 0 : 8192;
      if (EMB) { va0 = pack8(fa0, fa1); va1 = pack8(fa2, fa3); }
      *(uint4*)&ldsA[na + ld0] = va0;          *(uint4*)&ldsA[na + 2048 + ld0] = va1;
      *(uint4*)&ldsB[nb + ld0] = vb00;         *(uint4*)&ldsB[nb + 4096 + ld0] = vb01;
      *(uint4*)&ldsB[nb + 2048 + ld0] = vb10;  *(uint4*)&ldsB[nb + 6144 + ld0] = vb11;
    }
    asm volatile("s_waitcnt lgkmcnt(0)" ::: "memory");
    __builtin_amdgcn_s_barrier();
    __builtin_amdgcn_sched_barrier(0);
    p ^= 1;
  }
}

// ---- fused QKV + embedding gather: C[16384,1536] -> q/k/v [16384,512] each
__global__ __launch_bounds__(256, 3) void gemm_qkv(
    const float* __restrict__ embed,        // [32000,512] fp32
    const int* __restrict__ inputs,         // [16384]
    const unsigned short* __restrict__ WT,  // [1536,512] bf16 (Wq^T;Wk^T;Wv^T)
    const float* __restrict__ bq, const float* __restrict__ bk, const float* __restrict__ bv,
    unsigned short* __restrict__ q, unsigned short* __restrict__ kx, unsigned short* __restrict__ v)
{
  __shared__ unsigned short ldsA[8192], ldsB[16384];
  int bx, by;
  xcd_swz2(bx, by);
  const int m0 = by * 64, n0 = bx * 128;
  floatx4 acc[2][4];
#pragma unroll
  for (int i = 0; i < 2; i++)
#pragma unroll
    for (int j = 0; j < 4; j++) acc[i][j] = (floatx4){0.f, 0.f, 0.f, 0.f};

  kloop64<true>(nullptr, embed, inputs + m0, WT + (size_t)n0 * 512, 512, ldsA, ldsB, acc);

  const int seg = n0 >> 9, nloc = n0 & 511;
  unsigned short* C = seg == 0 ? q : (seg == 1 ? kx : v);
  const float* bias = seg == 0 ? bq : (seg == 1 ? bk : bv);
  const int lane = threadIdx.x & 63, w = threadIdx.x >> 6;
  const int quad = lane >> 4, l16 = lane & 15, wy = w >> 1, wx = w & 1;
  float bvv[4];
#pragma unroll
  for (int j = 0; j < 4; j++) bvv[j] = bias[nloc + wx * 64 + j * 16 + l16];
#pragma unroll
  for (int i = 0; i < 2; i++)
#pragma unroll
    for (int r = 0; r < 4; r++) {
      int m = m0 + wy * 32 + i * 16 + quad * 4 + r;
      unsigned short* crow = C + (size_t)m * 512 + nloc + wx * 64 + l16;
#pragma unroll
      for (int j = 0; j < 4; j++) crow[j * 16] = f2b(acc[i][j][r] + bvv[j]);
    }
}

// ---- generic bf16 GEMM: C = act(A @ Bt^T + bias), C fp32 (CF32) or bf16
template<int CF32, int ACT>
__global__ __launch_bounds__(256, 3) void gemm2(
    const unsigned short* __restrict__ A, const unsigned short* __restrict__ Bt,
    const float* __restrict__ bias, void* __restrict__ Cv,
    int N, int K, long aB, long bB, long cB)
{
  __shared__ unsigned short ldsA[8192], ldsB[16384];
  int bx, by;
  xcd_swz2(bx, by);
  const int b = blockIdx.z;
  const int m0 = by * 64, n0 = bx * 128;
  floatx4 acc[2][4];
#pragma unroll
  for (int i = 0; i < 2; i++)
#pragma unroll
    for (int j = 0; j < 4; j++) acc[i][j] = (floatx4){0.f, 0.f, 0.f, 0.f};

  kloop64<false>(A + (size_t)b * aB + (size_t)m0 * K, nullptr, nullptr,
                 Bt + (size_t)b * bB + (size_t)n0 * K, K, ldsA, ldsB, acc);

  const int lane = threadIdx.x & 63, w = threadIdx.x >> 6;
  const int quad = lane >> 4, l16 = lane & 15, wy = w >> 1, wx = w & 1;
  float bvv[4];
#pragma unroll
  for (int j = 0; j < 4; j++)
    bvv[j] = bias ? bias[n0 + wx * 64 + j * 16 + l16] : 0.f;
  float*          Cf = (float*)Cv          + (size_t)b * cB;
  unsigned short* Ch = (unsigned short*)Cv + (size_t)b * cB;
#pragma unroll
  for (int i = 0; i < 2; i++)
#pragma unroll
    for (int r = 0; r < 4; r++) {
      int m = m0 + wy * 32 + i * 16 + quad * 4 + r;
      size_t base = (size_t)m * N + n0 + wx * 64 + l16;
#pragma unroll
      for (int j = 0; j < 4; j++) {
        float vv = acc[i][j][r] + bvv[j];
        if (ACT == 1) vv = tanhf(vv);
        if (CF32) Cf[base + j * 16] = vv;
        else      Ch[base + j * 16] = f2b(vv);
      }
    }
}

// ---- score: E = dep ? exp(clamp((q.k)*dtab[dep])) : 0, fp32, coalesced epilogue
#define CST 132  // padded fp32 tile stride (floats): breaks row-bank aliasing
__global__ __launch_bounds__(256, 3) void score_kernel(
    const unsigned short* __restrict__ Q, const unsigned short* __restrict__ Km,
    const int* __restrict__ dep, const float* __restrict__ dept,
    float* __restrict__ E)
{
  __shared__ union {
    struct { unsigned short a[8192]; unsigned short b[16384]; } s;
    float c[32 * CST];
  } sm;
  __shared__ float dtab[64];
  const int tid = threadIdx.x;
  if (tid < 64) dtab[tid] = dept[tid];

  int bx, by;
  xcd_swz2(bx, by);
  const int b = blockIdx.z;
  const int m0 = by * 64, n0 = bx * 128;
  floatx4 acc[2][4];
#pragma unroll
  for (int i = 0; i < 2; i++)
#pragma unroll
    for (int j = 0; j < 4; j++) acc[i][j] = (floatx4){0.f, 0.f, 0.f, 0.f};

  kloop64<false>(Q + (size_t)b * (1024 * 512) + (size_t)m0 * 512, nullptr, nullptr,
                 Km + (size_t)b * (1024 * 512) + (size_t)n0 * 512, 512, sm.s.a, sm.s.b, acc);

  const int lane = tid & 63, w = tid >> 6;
  const int quad = lane >> 4, l16 = lane & 15, wy = w >> 1, wx = w & 1;
  const int* depb = dep + (size_t)b * 1024 * 1024;
  float* Eb = E + (size_t)b * 1024 * 1024;
  const int cr = tid >> 3, cb = (tid & 7) * 16;

#pragma unroll
  for (int i = 0; i < 2; i++) {
    __syncthreads();  // LDS free (kloop done / prior i's tile reads done)
#pragma unroll
    for (int j = 0; j < 4; j++)
#pragma unroll
      for (int r = 0; r < 4; r++)
        sm.c[(wy * 16 + quad * 4 + r) * CST + wx * 64 + j * 16 + l16] = acc[i][j][r];
    __syncthreads();
    // 32 rows x 128 cols; thread: row cr, 16 cols at cb -- all 16B accesses
    const int m = m0 + (cr >> 4) * 32 + i * 16 + (cr & 15);
    const int* dr = depb + (size_t)m * 1024 + n0 + cb;
    float* er = Eb + (size_t)m * 1024 + n0 + cb;
    const float* crow = &sm.c[cr * CST + cb];
#pragma unroll
    for (int c = 0; c < 4; c++) {
      int4 d = *(const int4*)(dr + c * 4);
      float4 s = *(const float4*)(crow + c * 4);
      float4 e;
      e.x = d.x ? __expf(fminf(fmaxf(s.x * dtab[d.x & 63], -60.f), 60.f)) : 0.f;
      e.y = d.y ? __expf(fminf(fmaxf(s.y * dtab[d.y & 63], -60.f), 60.f)) : 0.f;
      e.z = d.z ? __expf(fminf(fmaxf(s.z * dtab[d.z & 63], -60.f), 60.f)) : 0.f;
      e.w = d.w ? __expf(fminf(fmaxf(s.w * dtab[d.w & 63], -60.f), 60.f)) : 0.f;
      *(float4*)(er + c * 4) = e;
    }
  }
}

// ---- all 5 weight transposes fp32->bf16 in one launch (z selects source)
__global__ void trans_w(const float* s0, const float* s1, const float* s2,
                        const float* s3, const float* s4, unsigned short* dst)
{
  __shared__ unsigned short tile[32][33];
  const int z = blockIdx.z;
  const float* src = z == 0 ? s0 : z == 1 ? s1 : z == 2 ? s2 : z == 3 ? s3 : s4;
  unsigned short* ob = dst + (size_t)z * 262144;
  int c0 = blockIdx.x * 32, r0 = blockIdx.y * 32;
  int tx = threadIdx.x & 31, ty = threadIdx.x >> 5;
  for (int i = ty; i < 32; i += 8)
    tile[i][tx] = f2b(src[(size_t)(r0 + i) * 512 + (c0 + tx)]);
  __syncthreads();
  for (int i = ty; i < 32; i += 8)
    ob[(size_t)(c0 + i) * 512 + (r0 + tx)] = tile[tx][i];
}

// ---- bf16 transpose (v -> vT), batched
__global__ void trans_v(const unsigned short* __restrict__ in, unsigned short* __restrict__ out)
{
  __shared__ unsigned short tile[32][33];
  const unsigned short* ib = in + (size_t)blockIdx.z * (1024 * 512);
  unsigned short* ob = out + (size_t)blockIdx.z * (512 * 1024);
  int c0 = blockIdx.x * 32, r0 = blockIdx.y * 32;
  int tx = threadIdx.x & 31, ty = threadIdx.x >> 5;
  for (int i = ty; i < 32; i += 8)
    tile[i][tx] = ib[(size_t)(r0 + i) * 512 + (c0 + tx)];
  __syncthreads();
  for (int i = ty; i < 32; i += 8)
    ob[(size_t)(c0 + i) * 1024 + (r0 + tx)] = tile[tx][i];
}

// ---- rows /= rowsum; also emit bf16 copy for the PV GEMM
__global__ void normalize_rows(float* __restrict__ wf, unsigned short* __restrict__ wb)
{
  size_t row = blockIdx.x;
  float4* p = (float4*)(wf + row * 1024);
  float4 u = p[threadIdx.x];
  float s = (u.x + u.y) + (u.z + u.w);
#pragma unroll
  for (int d = 1; d < 64; d <<= 1) s += __shfl_xor(s, d);
  __shared__ float acc4[4];
  if ((threadIdx.x & 63) == 0) acc4[threadIdx.x >> 6] = s;
  __syncthreads();
  float tot = (acc4[0] + acc4[1]) + (acc4[2] + acc4[3]);
  float inv = tot > 0.f ? 1.f / tot : 0.f;
  u.x *= inv; u.y *= inv; u.z *= inv; u.w *= inv;
  p[threadIdx.x] = u;
  uint2 pk;
  pk.x = pk2(u.x, u.y);
  pk.y = pk2(u.z, u.w);
  *(uint2*)&wb[row * 1024 + threadIdx.x * 4] = pk;
}

extern "C" void kernel_launch(void* const* d_in, const int* in_sizes, int n_in,
                              void* d_out, int out_size, void* d_ws, size_t ws_size,
                              hipStream_t stream)
{
  const int*   inputs     = (const int*)d_in[0];
  const int*   dependency = (const int*)d_in[1];
  const float* embed      = (const float*)d_in[2];
  const float* dept       = (const float*)d_in[3];
  const float* Wq = (const float*)d_in[4];   const float* bq = (const float*)d_in[5];
  const float* Wk = (const float*)d_in[6];   const float* bk = (const float*)d_in[7];
  const float* Wv = (const float*)d_in[8];   const float* bvv = (const float*)d_in[9];
  const float* W1 = (const float*)d_in[10];  const float* b1 = (const float*)d_in[11];
  const float* W2 = (const float*)d_in[12];  const float* b2 = (const float*)d_in[13];

  float* out  = (float*)d_out;                       // wm [16,1024,512] fp32 (32 MB)
  float* wout = out + (size_t)8388608;               // weights [16,1024,1024] fp32 (64 MB)

  // ws (shorts):
  //  [0 .. 8388608)        q          -> wbf lo -> h
  //  [8388608 .. 16777216) kx         -> wbf hi
  //  [16777216 .. )        WTcat(3x) W1T W2T  (end 18087936)
  unsigned short* ws   = (unsigned short*)d_ws;
  unsigned short* q    = ws;
  unsigned short* kx   = ws + 8388608;
  unsigned short* WTc  = ws + 16777216;
  unsigned short* W1T  = ws + 17563648;
  unsigned short* W2T  = ws + 17825792;
  unsigned short* wbf  = ws;                          // [16384,1024] bf16 (32 MB)
  unsigned short* h    = ws;                          // [16384,512] bf16

  // output regions used as staging (dead before final writes):
  unsigned short* v    = (unsigned short*)out;        // [16384,512] bf16 in wm region lo
  unsigned short* vT   = (unsigned short*)out + 8388608;  // [16,512,1024] bf16 in wm hi
  unsigned short* wmp  = (unsigned short*)out;        // [16384,512] bf16 (over dead v)

  dim3 blk(256);

  trans_w<<<dim3(16, 16, 5), blk, 0, stream>>>(Wq, Wk, Wv, W1, W2, WTc);

  // embed gather fused into the A-staging (build_x eliminated)
  gemm_qkv<<<dim3(12, 256, 1), blk, 0, stream>>>(embed, inputs, WTc, bq, bk, bvv, q, kx, v);

  score_kernel<<<dim3(8, 16, 16), blk, 0, stream>>>(q, kx, dependency, dept, wout);

  trans_v<<<dim3(16, 32, 16), blk, 0, stream>>>(v, vT);

  normalize_rows<<<dim3(16384), blk, 0, stream>>>(wout, wbf);

  // wm_pre = weights @ v   (bf16 x bf16, batched)
  gemm2<0, 0><<<dim3(4, 16, 16), blk, 0, stream>>>(wbf, vT, nullptr, wmp,
                                                   512, 1024, 1024L * 1024, 512L * 1024, 1024L * 512);
  // h = tanh(wm_pre @ W1^T + b1)
  gemm2<0, 1><<<dim3(4, 256, 1), blk, 0, stream>>>(wmp, W1T, b1, h, 512, 512, 0, 0, 0);
  // wm = h @ W2^T + b2  (fp32, overwrites wmp/vT staging -- both dead)
  gemm2<1, 0><<<dim3(4, 256, 1), blk, 0, stream>>>(h, W2T, b2, out, 512, 512, 0, 0, 0);
}